// Round 12
// baseline (197.678 us; speedup 1.0000x reference)
//
#include <hip/hip_runtime.h>

// Problem constants (fixed by setup_inputs: bs=8, N=M=4096, C=128)
#define BS 8
#define NN 4096
#define MM 4096
#define CC 128
#define XT 128            // x rows per block
#define YT 128            // y rows per t-tile
#define MH 2048           // y rows per block
#define NMT (MH / YT)     // 16 y-tiles per block
#define NPH (2 * NMT)     // 32 half-K pipeline phases
#define NXT (NN / XT)     // 32 x-tiles
#define NBLK (BS * NXT * (MM / MH))   // 512 tile blocks
#define SLICE (YT * 64)   // ushorts per half-K slice (16 KB)

#define FINF_BITS 0x7F800000u

typedef __attribute__((ext_vector_type(8))) short bf16x8;
typedef __attribute__((ext_vector_type(4))) float f32x4;

// counted vmcnt wait (n = allowed outstanding VMEM ops)
#define WAITVn(n) asm volatile("s_waitcnt vmcnt(" #n ")" ::: "memory")
// rule #18: pin scheduling around barriers
#define SCHED_FENCE() __builtin_amdgcn_sched_barrier(0)

// RNE fp32 -> bf16 (inputs are finite normals)
__device__ inline ushort f2bf(float f) {
    unsigned u = __float_as_uint(f);
    unsigned r = (u + 0x7FFFu + ((u >> 16) & 1u)) >> 16;
    return (ushort)r;
}

// ---------------------------------------------------------------------------
// prep (y only): fp32->bf16 copy of set2 + exact fp32 y norms +
// rowmin/colmin=+inf + out=0 + done_ctr=0. 8 elem/thread.
// ---------------------------------------------------------------------------
__global__ void ch_prep(const float* __restrict__ y,
                        ushort* __restrict__ y16, float* __restrict__ yn,
                        unsigned* __restrict__ rowmin, unsigned* __restrict__ colmin,
                        float* __restrict__ out, unsigned* __restrict__ done_ctr) {
    int gid = blockIdx.x * blockDim.x + threadIdx.x;   // 524288 threads
    size_t i = (size_t)gid * 8;

    float4 w0 = *(const float4*)(y + i);
    float4 w1 = *(const float4*)(y + i + 4);
    ushort h[8] = {f2bf(w0.x), f2bf(w0.y), f2bf(w0.z), f2bf(w0.w),
                   f2bf(w1.x), f2bf(w1.y), f2bf(w1.z), f2bf(w1.w)};
    *(bf16x8*)(y16 + i) = *(bf16x8*)h;
    float sy = w0.x * w0.x + w0.y * w0.y + w0.z * w0.z + w0.w * w0.w +
               w1.x * w1.x + w1.y * w1.y + w1.z * w1.z + w1.w * w1.w;

#pragma unroll
    for (int mask = 1; mask <= 8; mask <<= 1)
        sy += __shfl_xor(sy, mask, 64);
    if ((threadIdx.x & 15) == 0)
        yn[gid >> 4] = sy;                 // 16 threads per 128-ch row

    if (gid < BS * NN) rowmin[gid] = FINF_BITS;
    if (gid < BS * MM) colmin[gid] = FINF_BITS;
    if (gid == 0) { out[0] = 0.0f; *done_ctr = 0u; }
}

// stage one half-K slice (128 rows x 64 k = 16 KB) of y tile via
// global_load_lds width-16, dest lane-order, source chunk-swizzled c^(r&7).
// 256 threads: 1024 chunks -> 4 iterations. Counts 4 on vmcnt per wave.
__device__ __forceinline__ void stage_y(const ushort* __restrict__ Yb,
                                        ushort* __restrict__ buf,
                                        int tile, int half, int tid, int wave) {
#pragma unroll
    for (int s = 0; s < 4; ++s) {
        int f = s * 256 + tid;           // 1024 chunks = 128 rows x 8
        int r = f >> 3, cslot = f & 7;
        const ushort* g = Yb + (size_t)(tile * YT + r) * CC + half * 64 +
                          ((cslot ^ (r & 7)) * 8);
        ushort* l = buf + (size_t)(s * 256 + wave * 64) * 8;  // uniform; HW adds lane*16
        __builtin_amdgcn_global_load_lds(
            (const __attribute__((address_space(1))) void*)g,
            (__attribute__((address_space(3))) void*)l, 16, 0, 0);
    }
}

// ---------------------------------------------------------------------------
// main kernel (R27 = R19 body verbatim + fused last-block finalize).
// R26's cooperative fusion returned out==0 (absmax == full ref value):
// hipLaunchCooperativeKernel under graph capture most likely never ran.
// Same goal, capture-safe mechanism: after each block's global flush,
// __threadfence + atomicAdd(done_ctr); the block observing NBLK-1 runs the
// finalize in-place. Coherence via device-scope atomics only (G16):
// rowmin/colmin are READ with atomicMin(p, FINF_BITS) -- a no-op RMW that
// returns the current value through the coherent path (min(x,+inf)=x), so
// no stale-L2 exposure; flush atomicMins -> release fence -> counter
// observed => visible. No spin-waits, no dispatch-order assumptions.
// The R19 compute body (x-in-reg af[4][4], 3-slice counted-vmcnt(4)
// pipeline, per-phase s_barrier, c^(r&7) swizzles) is unchanged -- best
// of 8 measured structures (50.6us, MfmaUtil 25, conflicts 131K).
// ---------------------------------------------------------------------------
__global__ __launch_bounds__(256, 2) void ch_tile(
    const float* __restrict__ Xf, const ushort* __restrict__ Y,
    const float* __restrict__ yn,
    unsigned* __restrict__ rowmin, unsigned* __restrict__ colmin,
    const float* __restrict__ w1, const float* __restrict__ w2,
    float* __restrict__ out, unsigned* __restrict__ done_ctr) {

    __shared__ ushort pool[3 * SLICE];   // 48 KB: xs (32 KB) then 3 y slices
    __shared__ unsigned coltile[MH];     // 8 KB
    __shared__ unsigned rowtile[XT];     // 0.5 KB
    __shared__ float xnorm[XT];          // 0.5 KB
    __shared__ float ynld[MH];           // 8 KB (block's y norms)
    __shared__ unsigned lastblk;         // fused-finalize flag
    __shared__ float ls[4];              // fused-finalize scratch

    const int b  = blockIdx.x;           // 0..7 -> XCD pin (linear id % 8 == b)
    const int xt = blockIdx.y;           // 0..31
    const int mh = blockIdx.z;           // 0..1
    const int n0 = xt * XT;
    const int m0 = mh * MH;
    const int tid  = threadIdx.x;        // 0..255
    const int lane = tid & 63;
    const int wave = tid >> 6;           // 0..3
    const int lc   = lane & 15;          // A/B row, C col
    const int quad = lane >> 4;          // k-chunk, C row group
    const int wm = wave >> 1;            // x half (0/1)
    const int wn = wave & 1;             // y half (0/1)

    const ushort* Yb = Y + ((size_t)b * MM + m0) * CC;

    // ---- prologue A: stage x tile fp32 -> bf16 -> swizzled LDS (xs = pool);
    //      x norms; y norms -> LDS; coltile/rowtile init ----
    ushort* xs = pool;
    const float* Xb = Xf + ((size_t)b * NN + n0) * CC;
    {
        float psum[8];
#pragma unroll
        for (int s = 0; s < 8; ++s) {
            int flat = s * 256 + tid;    // 2048 chunks = 128 rows x 16
            int r = flat >> 4, c = flat & 15;
            float4 v0 = *(const float4*)(Xb + (size_t)r * CC + c * 8);
            float4 v1 = *(const float4*)(Xb + (size_t)r * CC + c * 8 + 4);
            ushort h[8] = {f2bf(v0.x), f2bf(v0.y), f2bf(v0.z), f2bf(v0.w),
                           f2bf(v1.x), f2bf(v1.y), f2bf(v1.z), f2bf(v1.w)};
            *(bf16x8*)(xs + r * CC + (c ^ (r & 7)) * 8) = *(bf16x8*)h;
            psum[s] = v0.x * v0.x + v0.y * v0.y + v0.z * v0.z + v0.w * v0.w +
                      v1.x * v1.x + v1.y * v1.y + v1.z * v1.z + v1.w * v1.w;
        }
#pragma unroll
        for (int mask = 1; mask <= 8; mask <<= 1)
#pragma unroll
            for (int s = 0; s < 8; ++s)
                psum[s] += __shfl_xor(psum[s], mask, 64);
        if ((tid & 15) == 0) {
#pragma unroll
            for (int s = 0; s < 8; ++s)
                xnorm[s * 16 + (tid >> 4)] = psum[s];
        }
    }
    {
        const float* ynb = yn + (size_t)b * MM + m0;
#pragma unroll
        for (int s = 0; s < MH / 256; ++s)
            ynld[s * 256 + tid] = ynb[s * 256 + tid];
    }
    for (int c2 = tid; c2 < MH; c2 += 256) coltile[c2] = FINF_BITS;
    if (tid < XT) rowtile[tid] = FINF_BITS;

    __syncthreads();   // xs + xnorm + ynld + coltile ready

    // ---- prologue B: hoist this wave's A operand + norms into registers ----
    bf16x8 af[4][4];   // [k-chunk32 kt][row-group i] : 64 VGPR
    const int xrow = (wm * 64 + lc) * CC;
    const int xsw  = lc & 7;
#pragma unroll
    for (int kt = 0; kt < 4; ++kt)
#pragma unroll
        for (int i = 0; i < 4; ++i)
            af[kt][i] = *(const bf16x8*)(xs + xrow + i * 16 * CC +
                                         ((kt * 4 + quad) ^ xsw) * 8);

    float xnp[4][4];
#pragma unroll
    for (int i = 0; i < 4; ++i) {
        float4 t = *(const float4*)(&xnorm[wm * 64 + i * 16 + quad * 4]);
        xnp[i][0] = t.x; xnp[i][1] = t.y; xnp[i][2] = t.z; xnp[i][3] = t.w;
    }
    float rm[4][4];
#pragma unroll
    for (int i = 0; i < 4; ++i)
#pragma unroll
        for (int r = 0; r < 4; ++r) rm[i][r] = __builtin_inff();

    __syncthreads();   // all waves done reading xs: pool may be overwritten

    // ---- prologue C: stage slices 0,1 into buffers 0,1 ----
    stage_y(Yb, pool + 0 * SLICE, 0, 0, tid, wave);
    stage_y(Yb, pool + 1 * SLICE, 0, 1, tid, wave);
    WAITVn(4);                       // slice 0 landed; slice 1 in flight
    __builtin_amdgcn_s_barrier();
    SCHED_FENCE();

    int rd = 0;                      // buffer holding the current slice
#pragma unroll 1
    for (int t = 0; t < NMT; ++t) {
        f32x4 acc[4][4];
        const f32x4 z = {0.f, 0.f, 0.f, 0.f};
        float ynr[4];

        // ================= phase h=0 (k 0..63) =================
        {
            const int ph = 2 * t;
            const ushort* ybuf = pool + rd * SLICE;
            if (ph + 2 < NPH) {
                int wr = rd + 2; if (wr >= 3) wr -= 3;
                stage_y(Yb, pool + wr * SLICE, (ph + 2) >> 1, (ph + 2) & 1,
                        tid, wave);
            }
#pragma unroll
            for (int j = 0; j < 4; ++j)       // LDS read: no vmcnt impact
                ynr[j] = ynld[t * YT + wn * 64 + j * 16 + lc];
#pragma unroll
            for (int s2 = 0; s2 < 2; ++s2) {
                bf16x8 yf[4];
                const int cy = ((s2 * 4 + quad) ^ xsw) * 8;
#pragma unroll
                for (int j = 0; j < 4; ++j)
                    yf[j] = *(const bf16x8*)(ybuf + (wn * 64 + j * 16 + lc) * 64 + cy);
                __builtin_amdgcn_s_setprio(1);
#pragma unroll
                for (int j = 0; j < 4; ++j)
#pragma unroll
                    for (int i = 0; i < 4; ++i)
                        acc[i][j] = __builtin_amdgcn_mfma_f32_16x16x32_bf16(
                            af[s2][i], yf[j], (s2 == 0) ? z : acc[i][j], 0, 0, 0);
                __builtin_amdgcn_s_setprio(0);
            }
            SCHED_FENCE();
            if (ph + 2 < NPH) { WAITVn(4); } else { WAITVn(0); }
            __builtin_amdgcn_s_barrier();
            SCHED_FENCE();
            rd = (rd == 2) ? 0 : rd + 1;
        }

        // ================= phase h=1 (k 64..127) =================
        {
            const int ph = 2 * t + 1;
            const ushort* ybuf = pool + rd * SLICE;
            if (ph + 2 < NPH) {
                int wr = rd + 2; if (wr >= 3) wr -= 3;
                stage_y(Yb, pool + wr * SLICE, (ph + 2) >> 1, (ph + 2) & 1,
                        tid, wave);
            }
#pragma unroll
            for (int s2 = 0; s2 < 2; ++s2) {
                bf16x8 yf[4];
                const int cy = ((s2 * 4 + quad) ^ xsw) * 8;
#pragma unroll
                for (int j = 0; j < 4; ++j)
                    yf[j] = *(const bf16x8*)(ybuf + (wn * 64 + j * 16 + lc) * 64 + cy);
                __builtin_amdgcn_s_setprio(1);
#pragma unroll
                for (int j = 0; j < 4; ++j)
#pragma unroll
                    for (int i = 0; i < 4; ++i)
                        acc[i][j] = __builtin_amdgcn_mfma_f32_16x16x32_bf16(
                            af[2 + s2][i], yf[j], acc[i][j], 0, 0, 0);
                __builtin_amdgcn_s_setprio(0);
            }

            // ---- epilogue: d^2 mins (sqrt/clamp deferred) ----
            float cmv[4];
#pragma unroll
            for (int j = 0; j < 4; ++j) cmv[j] = __builtin_inff();
#pragma unroll
            for (int i = 0; i < 4; ++i) {
#pragma unroll
                for (int j = 0; j < 4; ++j) {
                    f32x4 a = acc[i][j];
                    float e[4];
#pragma unroll
                    for (int r = 0; r < 4; ++r)
                        e[r] = xnp[i][r] + fmaf(-2.0f, a[r], ynr[j]);
#pragma unroll
                    for (int r = 0; r < 4; ++r)
                        rm[i][r] = fminf(rm[i][r], e[r]);
                    cmv[j] = fminf(cmv[j],
                                   fminf(fminf(e[0], e[1]), fminf(e[2], e[3])));
                }
            }
#pragma unroll
            for (int mask = 16; mask <= 32; mask <<= 1)
#pragma unroll
                for (int j = 0; j < 4; ++j)
                    cmv[j] = fminf(cmv[j], __shfl_xor(cmv[j], mask, 64));
            if (quad == 0) {
#pragma unroll
                for (int j = 0; j < 4; ++j)
                    atomicMin(&coltile[t * YT + wn * 64 + j * 16 + lc],
                              __float_as_uint(fmaxf(cmv[j], 0.0f)));
            }

            SCHED_FENCE();
            if (ph + 2 < NPH) { WAITVn(4); } else { WAITVn(0); }
            __builtin_amdgcn_s_barrier();
            SCHED_FENCE();
            rd = (rd == 2) ? 0 : rd + 1;
        }
    }

    // ---- row mins: reduce across the 16 lc lanes, LDS atomic once ----
#pragma unroll
    for (int mask = 1; mask <= 8; mask <<= 1)
#pragma unroll
        for (int i = 0; i < 4; ++i)
#pragma unroll
            for (int r = 0; r < 4; ++r)
                rm[i][r] = fminf(rm[i][r], __shfl_xor(rm[i][r], mask, 64));
    if (lc == 0) {
#pragma unroll
        for (int i = 0; i < 4; ++i)
#pragma unroll
            for (int r = 0; r < 4; ++r)
                atomicMin(&rowtile[wm * 64 + i * 16 + quad * 4 + r],
                          __float_as_uint(fmaxf(rm[i][r], 0.0f)));
    }

    // ---- flush tile minima with global atomics ----
    __syncthreads();
    if (tid < XT)
        atomicMin(&rowmin[(size_t)b * NN + n0 + tid], rowtile[tid]);
    for (int c2 = tid; c2 < MH; c2 += 256)
        atomicMin(&colmin[(size_t)b * MM + m0 + c2], coltile[c2]);

    // ---- fused finalize: last block to arrive does the reduction ----
    __threadfence();          // release: flush atomics ordered before counter
    __syncthreads();          // whole block's flushes + fences complete
    if (tid == 0) {
        unsigned my = atomicAdd(done_ctr, 1u);
        lastblk = (my == (unsigned)(NBLK - 1)) ? 1u : 0u;
    }
    __syncthreads();
    if (lastblk) {
        float s = 0.f;
        for (int idx = tid; idx < BS * NN; idx += 256) {
            // coherent read-through-atomic: min(x, +inf) == x, returns old
            unsigned rv = atomicMin(&rowmin[idx], FINF_BITS);
            unsigned cv = atomicMin(&colmin[idx], FINF_BITS);
            s += w1[idx] * sqrtf(__uint_as_float(rv)) +
                 w2[idx] * sqrtf(__uint_as_float(cv));
        }
#pragma unroll
        for (int off = 32; off > 0; off >>= 1) s += __shfl_down(s, off, 64);
        if (lane == 0) ls[wave] = s;
        __syncthreads();
        if (tid == 0) {
            float tot = ls[0] + ls[1] + ls[2] + ls[3];
            atomicAdd(out, 0.5f * tot);
        }
    }
}

extern "C" void kernel_launch(void* const* d_in, const int* in_sizes, int n_in,
                              void* d_out, int out_size, void* d_ws, size_t ws_size,
                              hipStream_t stream) {
    const float* set1 = (const float*)d_in[0];
    const float* set2 = (const float*)d_in[1];
    const float* w1   = (const float*)d_in[2];
    const float* w2   = (const float*)d_in[3];
    float* out = (float*)d_out;

    // workspace layout (~8.5 MiB)
    ushort*   y16     = (ushort*)d_ws;                        // BS*MM*CC bf16 (8 MB)
    float*    yn      = (float*)(y16 + (size_t)BS * MM * CC); // 128 KB
    unsigned* rowmin  = (unsigned*)(yn + BS * MM);            // 128 KB (d^2 bits)
    unsigned* colmin  = rowmin + BS * NN;                     // 128 KB (d^2 bits)
    unsigned* done    = colmin + BS * MM;                     // 4 B

    ch_prep<<<BS * MM * CC / 8 / 256, 256, 0, stream>>>(
        set2, y16, yn, rowmin, colmin, out, done);

    dim3 grid(BS, NXT, MM / MH);   // b fastest -> linear id % 8 == b == XCD
    ch_tile<<<grid, 256, 0, stream>>>(set1, y16, yn, rowmin, colmin,
                                      w1, w2, out, done);
}